// Round 3
// baseline (881.154 us; speedup 1.0000x reference)
//
#include <hip/hip_runtime.h>
#include <math.h>

#define B_ROWS 16384
#define D_DIM  2048
#define H_DIM  512
#define RESCUE_EPS 0.01

typedef __attribute__((ext_vector_type(8))) short  s16x8;  // 8 bf16
typedef __attribute__((ext_vector_type(4))) float  f32x4;  // MFMA acc

union U8 { unsigned short us[8]; s16x8 v; };

static __device__ __forceinline__ unsigned short f2bf(float f) {
    unsigned u = __float_as_uint(f);
    u += 0x7FFFu + ((u >> 16) & 1u);   // RNE (no NaN inputs here)
    return (unsigned short)(u >> 16);
}

// ---------------- Kernel 0: pack W1 -> bf16 hi/lo in MFMA B-fragment order ----------------
// Fragment layout (16x16x32): lane l holds B[k=(l>>4)*8+j][n=l&15], j=0..7.
// Wp[type][s=k>>5][NtG=n>>4][lane][j], 2 types x 64 s x 32 Nt x 64 lanes x 8 bf16 = 4 MB.
__global__ __launch_bounds__(256) void pack_w1(
    const float* __restrict__ W1, unsigned short* __restrict__ Wp)
{
    const int gid = blockIdx.x * 256 + threadIdx.x;   // 131072 = 256 k-octets x 512 n
    const int ko = gid >> 9;          // k-octet 0..255
    const int n  = gid & 511;
    U8 h8, l8;
    #pragma unroll
    for (int j = 0; j < 8; ++j) {
        const float w = W1[(size_t)(ko * 8 + j) * H_DIM + n];
        const unsigned short h = f2bf(w);
        const float hf = __uint_as_float((unsigned)h << 16);
        h8.us[j] = h;
        l8.us[j] = f2bf(w - hf);
    }
    const int s    = ko >> 2;
    const int lane = (n & 15) | ((ko & 3) << 4);
    const int Nt   = n >> 4;
    const size_t baseH = ((((size_t)0 * 64 + s) * 32 + Nt) * 64 + lane) * 8;
    const size_t baseL = ((((size_t)1 * 64 + s) * 32 + Nt) * 64 + lane) * 8;
    *(s16x8*)(Wp + baseH) = h8.v;
    *(s16x8*)(Wp + baseL) = l8.v;
}

// ---------------- Kernel 1: predictor GEMM via bf16 MFMA, 3-product split ----------------
// Block: 64 rows x 256 cols, 256 threads (4 waves, one per 64-col slice).
// Wave: 4 Mt x 4 Nt tiles of 16x16, BK=32 (one mfma_16x16x32 k-instr), 48 MFMA/step.
// A (x) -> LDS double-buffered in fragment order; B frags direct global->VGPR (packed Wp).
__global__ __launch_bounds__(256, 2) void predictor_gemm(
    const float* __restrict__ x, const unsigned short* __restrict__ Wp,
    const float* __restrict__ b1, const float* __restrict__ W2,
    double* __restrict__ logit)
{
    // Abuf[buf][type][Mt*512 + lane*8 + j]  (4 Mt x 64 lanes x 8 bf16 per type)
    __shared__ __align__(16) unsigned short Abuf[2][2][4 * 64 * 8];

    const int tid = threadIdx.x;
    const int l   = tid & 63;        // lane
    const int Nw  = tid >> 6;        // wave id = 64-col slice
    const int bx  = blockIdx.x;      // row block (64 rows)
    const int by  = blockIdx.y;      // col block (256 cols)
    const int rowBase = bx * 64;

    // staging role: thread t stages row m, k-octet ko of the 64x32 x-tile
    const int sm = tid >> 2;         // 0..63
    const int sko = tid & 3;         // 0..3
    const float* xrow_p = x + (size_t)(rowBase + sm) * D_DIM + sko * 8;
    const int aMt   = sm >> 4;
    const int aLane = (sm & 15) | (sko << 4);
    unsigned short* aDstH[2] = {&Abuf[0][0][aMt * 512 + aLane * 8],
                                &Abuf[1][0][aMt * 512 + aLane * 8]};
    unsigned short* aDstL[2] = {&Abuf[0][1][aMt * 512 + aLane * 8],
                                &Abuf[1][1][aMt * 512 + aLane * 8]};

    const s16x8* WpV = (const s16x8*)Wp;   // 16-B frag granules
    // frag index: ((type*64 + s)*32 + NtG)*64 + l
    const int NtBase = by * 16 + Nw * 4;

    f32x4 acc[4][4];
    #pragma unroll
    for (int mt = 0; mt < 4; ++mt)
        #pragma unroll
        for (int nt = 0; nt < 4; ++nt)
            acc[mt][nt] = {0.f, 0.f, 0.f, 0.f};

    // ---- prologue: stage A(0), load B(0) ----
    float4 xa = *(const float4*)(xrow_p);
    float4 xb = *(const float4*)(xrow_p + 4);
    {
        U8 h8, l8;
        const float xv[8] = {xa.x, xa.y, xa.z, xa.w, xb.x, xb.y, xb.z, xb.w};
        #pragma unroll
        for (int i = 0; i < 8; ++i) {
            const unsigned short h = f2bf(xv[i]);
            h8.us[i] = h;
            l8.us[i] = f2bf(xv[i] - __uint_as_float((unsigned)h << 16));
        }
        *(s16x8*)aDstH[0] = h8.v;
        *(s16x8*)aDstL[0] = l8.v;
    }
    s16x8 Bh[4], Bl[4];
    #pragma unroll
    for (int nt = 0; nt < 4; ++nt) {
        Bh[nt] = WpV[((0 * 64 + 0) * 32 + NtBase + nt) * 64 + l];
        Bl[nt] = WpV[((1 * 64 + 0) * 32 + NtBase + nt) * 64 + l];
    }
    __syncthreads();

    for (int s = 0; s < 64; ++s) {
        const int cur = s & 1, nxt = cur ^ 1;
        s16x8 BhN[4], BlN[4];
        if (s < 63) {
            // prefetch next B frags (L2-resident packed W1) and next x tile
            #pragma unroll
            for (int nt = 0; nt < 4; ++nt) {
                BhN[nt] = WpV[((0 * 64 + (s + 1)) * 32 + NtBase + nt) * 64 + l];
                BlN[nt] = WpV[((1 * 64 + (s + 1)) * 32 + NtBase + nt) * 64 + l];
            }
            xa = *(const float4*)(xrow_p + (s + 1) * 32);
            xb = *(const float4*)(xrow_p + (s + 1) * 32 + 4);
        }

        // A fragments from LDS (canonical lane-contiguous b128 reads)
        s16x8 Ah[4], Al[4];
        #pragma unroll
        for (int mt = 0; mt < 4; ++mt) {
            Ah[mt] = *(const s16x8*)&Abuf[cur][0][mt * 512 + l * 8];
            Al[mt] = *(const s16x8*)&Abuf[cur][1][mt * 512 + l * 8];
        }

        // 48 MFMAs: hi*hi + lo*hi + hi*lo
        #pragma unroll
        for (int mt = 0; mt < 4; ++mt)
            #pragma unroll
            for (int nt = 0; nt < 4; ++nt) {
                acc[mt][nt] = __builtin_amdgcn_mfma_f32_16x16x32_bf16(Ah[mt], Bh[nt], acc[mt][nt], 0, 0, 0);
                acc[mt][nt] = __builtin_amdgcn_mfma_f32_16x16x32_bf16(Al[mt], Bh[nt], acc[mt][nt], 0, 0, 0);
                acc[mt][nt] = __builtin_amdgcn_mfma_f32_16x16x32_bf16(Ah[mt], Bl[nt], acc[mt][nt], 0, 0, 0);
            }

        if (s < 63) {
            U8 h8, l8;
            const float xv[8] = {xa.x, xa.y, xa.z, xa.w, xb.x, xb.y, xb.z, xb.w};
            #pragma unroll
            for (int i = 0; i < 8; ++i) {
                const unsigned short h = f2bf(xv[i]);
                h8.us[i] = h;
                l8.us[i] = f2bf(xv[i] - __uint_as_float((unsigned)h << 16));
            }
            *(s16x8*)aDstH[nxt] = h8.v;
            *(s16x8*)aDstL[nxt] = l8.v;
            #pragma unroll
            for (int nt = 0; nt < 4; ++nt) { Bh[nt] = BhN[nt]; Bl[nt] = BlN[nt]; }
        }
        __syncthreads();
    }

    // ---- epilogue: +b1, relu, fp64 dot with W2, cross-lane reduce, atomic ----
    float  b1v[4];
    double w2v[4];
    #pragma unroll
    for (int nt = 0; nt < 4; ++nt) {
        const int j = by * 256 + (Nw * 4 + nt) * 16 + (l & 15);
        b1v[nt] = b1[j];
        w2v[nt] = (double)W2[j];
    }
    #pragma unroll
    for (int mt = 0; mt < 4; ++mt)
        #pragma unroll
        for (int reg = 0; reg < 4; ++reg) {
            double p = 0.0;
            #pragma unroll
            for (int nt = 0; nt < 4; ++nt) {
                const float h = acc[mt][nt][reg] + b1v[nt];
                if (h > 0.0f) p = fma((double)h, w2v[nt], p);
            }
            #pragma unroll
            for (int m2 = 1; m2 < 16; m2 <<= 1) p += __shfl_xor(p, m2, 64);
            if ((l & 15) == 0)
                atomicAdd(&logit[rowBase + mt * 16 + ((l >> 4) & 3) * 4 + reg], p);
        }
}

// ------------- Kernel 2: per-row radix-select threshold + rescue + writeback -------------
__global__ __launch_bounds__(256) void select_and_write(
    const float* __restrict__ x, const float* __restrict__ W1,
    const float* __restrict__ b1, const float* __restrict__ W2,
    const float* __restrict__ b2, const double* __restrict__ logit,
    float* __restrict__ out_sparse, float* __restrict__ out_mask,
    float* __restrict__ out_sparsity, float* __restrict__ out_actual,
    double* __restrict__ l1rows)
{
    __shared__ float  xrow[2048];
    __shared__ int    histW[4 * 256];
    __shared__ int    histA[256];
    __shared__ int    sh_k;
    __shared__ int    sh_resc;
    __shared__ int    sh_digit;
    __shared__ int    sh_krem;
    __shared__ double wsum[4];
    __shared__ double dred[4];
    __shared__ int    wcnt[4];

    const int row = blockIdx.x;
    const int tid = threadIdx.x;
    const float4* xr4 = (const float4*)(x + (size_t)row * D_DIM);

    const float4 va = xr4[tid];
    const float4 vb = xr4[tid + 256];
    float v[8] = {va.x, va.y, va.z, va.w, vb.x, vb.y, vb.z, vb.w};
    unsigned u[8];
    #pragma unroll
    for (int i = 0; i < 8; ++i) u[i] = __float_as_uint(v[i]) & 0x7FFFFFFFu;

    *(float4*)&xrow[tid * 4]        = va;   // for rescue path
    *(float4*)&xrow[1024 + tid * 4] = vb;

    if (tid == 0) {
        const double L = logit[row] + (double)b2[0];
        const double sig = 1.0 / (1.0 + exp(-L));
        const double s = 0.05 + 0.25 * sig;             // MIN_S + (MAX_S-MIN_S)*sig
        const double kf = 2048.0 * (1.0 - s);
        const double fr = kf - floor(kf);
        sh_resc = (fabs(fr - 0.5) < RESCUE_EPS) ? 1 : 0;
        int k = (int)rint(kf);                          // half-even, matches np.round
        if (k < 1) k = 1;
        if (k > 2048) k = 2048;
        sh_k = k;
        out_sparsity[row] = (float)s;
    }
    __syncthreads();

    if (sh_resc) {
        // exact fp64 recompute of logit: h_j = relu(x . W1[:,j] + b1[j]); L = sum h_j W2[j] + b2
        double pd = 0.0;
        #pragma unroll
        for (int jj = 0; jj < 2; ++jj) {
            const int j = tid + jj * 256;
            double a = (double)b1[j];
            for (int kk = 0; kk < 2048; kk += 4) {
                a = fma((double)xrow[kk],     (double)W1[(size_t)kk * H_DIM + j],       a);
                a = fma((double)xrow[kk + 1], (double)W1[(size_t)(kk + 1) * H_DIM + j], a);
                a = fma((double)xrow[kk + 2], (double)W1[(size_t)(kk + 2) * H_DIM + j], a);
                a = fma((double)xrow[kk + 3], (double)W1[(size_t)(kk + 3) * H_DIM + j], a);
            }
            if (a > 0.0) pd = fma(a, (double)W2[j], pd);
        }
        #pragma unroll
        for (int off = 32; off > 0; off >>= 1) pd += __shfl_down(pd, off);
        if ((tid & 63) == 0) dred[tid >> 6] = pd;
        __syncthreads();
        if (tid == 0) {
            const double L = dred[0] + dred[1] + dred[2] + dred[3] + (double)b2[0];
            const double sig = 1.0 / (1.0 + exp(-L));
            const double s = 0.05 + 0.25 * sig;
            int k = (int)rint(2048.0 * (1.0 - s));
            if (k < 1) k = 1;
            if (k > 2048) k = 2048;
            sh_k = k;
            out_sparsity[row] = (float)s;
        }
        __syncthreads();
    }

    int krem = sh_k;            // rank (1-indexed) of k-th SMALLEST |x|
    unsigned prefix = 0;

    // 4-pass MSD radix select on abs-bit pattern (monotone for non-negative floats)
    for (int pass = 0; pass < 4; ++pass) {
        const int shift = 24 - pass * 8;
        const unsigned pmask = (pass == 0) ? 0u : (0xFFFFFFFFu << (shift + 8));
        if (pass == 0) {
            // exponent byte is heavily clustered -> per-wave histograms cut contention 4x
            histW[tid] = 0; histW[256 + tid] = 0; histW[512 + tid] = 0; histW[768 + tid] = 0;
            __syncthreads();
            const int base = (tid >> 6) << 8;
            #pragma unroll
            for (int i = 0; i < 8; ++i)
                atomicAdd(&histW[base + ((u[i] >> 24) & 255)], 1);
            __syncthreads();
            histA[tid] = histW[tid] + histW[tid + 256] + histW[tid + 512] + histW[tid + 768];
        } else {
            histA[tid] = 0;
            __syncthreads();
            #pragma unroll
            for (int i = 0; i < 8; ++i)
                if ((u[i] & pmask) == prefix)
                    atomicAdd(&histA[(u[i] >> shift) & 255], 1);
        }
        __syncthreads();
        if (tid < 64) {
            const int b0 = histA[4 * tid + 0];
            const int b1_ = histA[4 * tid + 1];
            const int b2_ = histA[4 * tid + 2];
            const int b3_ = histA[4 * tid + 3];
            const int tot = b0 + b1_ + b2_ + b3_;
            int sc = tot;
            #pragma unroll
            for (int off = 1; off < 64; off <<= 1) {
                int n = __shfl_up(sc, off);
                if (tid >= off) sc += n;
            }
            const int excl = sc - tot;        // elems in bins < 4*tid
            const int c0 = excl, c1 = c0 + b0, c2 = c1 + b1_, c3 = c2 + b2_;
            int d = -1, cb = 0;
            if      (krem > c0 && krem <= c1)        { d = 4 * tid + 0; cb = c0; }
            else if (krem > c1 && krem <= c2)        { d = 4 * tid + 1; cb = c1; }
            else if (krem > c2 && krem <= c3)        { d = 4 * tid + 2; cb = c2; }
            else if (krem > c3 && krem <= c3 + b3_)  { d = 4 * tid + 3; cb = c3; }
            if (d >= 0) { sh_digit = d; sh_krem = krem - cb; }  // exactly one lane
        }
        __syncthreads();
        prefix |= ((unsigned)sh_digit) << shift;
        krem = sh_krem;
    }
    const unsigned thr = prefix;  // exact bit pattern of k-th smallest |x|

    // writeback: mask = (|x| > thr), bitwise-identical to reference float compare
    float m[8];
    int cnt = 0;
    double lp = 0.0;
    #pragma unroll
    for (int i = 0; i < 8; ++i) {
        const bool keep = (u[i] > thr);
        m[i] = keep ? 1.0f : 0.0f;
        cnt += keep ? 1 : 0;
        if (keep) lp += (double)fabsf(v[i]);
    }
    float4* os4 = (float4*)(out_sparse + (size_t)row * D_DIM);
    float4* om4 = (float4*)(out_mask   + (size_t)row * D_DIM);
    float4 s0 = {m[0] != 0.0f ? v[0] : 0.0f, m[1] != 0.0f ? v[1] : 0.0f,
                 m[2] != 0.0f ? v[2] : 0.0f, m[3] != 0.0f ? v[3] : 0.0f};
    float4 s1 = {m[4] != 0.0f ? v[4] : 0.0f, m[5] != 0.0f ? v[5] : 0.0f,
                 m[6] != 0.0f ? v[6] : 0.0f, m[7] != 0.0f ? v[7] : 0.0f};
    float4 m0 = {m[0], m[1], m[2], m[3]};
    float4 m1 = {m[4], m[5], m[6], m[7]};
    os4[tid]       = s0;
    os4[tid + 256] = s1;
    om4[tid]       = m0;
    om4[tid + 256] = m1;

    #pragma unroll
    for (int off = 32; off > 0; off >>= 1) {
        lp  += __shfl_down(lp, off);
        cnt += __shfl_down(cnt, off);
    }
    const int wave = tid >> 6, lane = tid & 63;
    if (lane == 0) { wsum[wave] = lp; wcnt[wave] = cnt; }
    __syncthreads();
    if (tid == 0) {
        const double t = wsum[0] + wsum[1] + wsum[2] + wsum[3];
        const int    c = wcnt[0] + wcnt[1] + wcnt[2] + wcnt[3];
        l1rows[row] = t;
        out_actual[row] = (float)c * (1.0f / 2048.0f);
    }
}

// ---------------- Kernel 3: reduce row L1 sums -> l1_reg ----------------
__global__ __launch_bounds__(256) void finalize_l1(
    const double* __restrict__ l1rows, float* __restrict__ out_l1)
{
    __shared__ double sh[256];
    double s = 0.0;
    for (int i = threadIdx.x; i < B_ROWS; i += 256) s += l1rows[i];
    sh[threadIdx.x] = s;
    __syncthreads();
    for (int st = 128; st > 0; st >>= 1) {
        if (threadIdx.x < st) sh[threadIdx.x] += sh[threadIdx.x + st];
        __syncthreads();
    }
    if (threadIdx.x == 0) out_l1[0] = (float)(sh[0] / (double)B_ROWS);
}

extern "C" void kernel_launch(void* const* d_in, const int* in_sizes, int n_in,
                              void* d_out, int out_size, void* d_ws, size_t ws_size,
                              hipStream_t stream) {
    const float* x  = (const float*)d_in[0];
    const float* W1 = (const float*)d_in[1];
    const float* b1 = (const float*)d_in[2];
    const float* W2 = (const float*)d_in[3];
    const float* b2 = (const float*)d_in[4];

    float* out = (float*)d_out;
    float* out_sparse   = out;                                   // B*D
    float* out_mask     = out + (size_t)B_ROWS * D_DIM;          // B*D
    float* out_sparsity = out + 2ull * B_ROWS * D_DIM;           // B
    float* out_actual   = out_sparsity + B_ROWS;                 // B
    float* out_l1       = out_actual + B_ROWS;                   // 1

    double* logit  = (double*)d_ws;                        // B doubles (atomics)
    double* l1rows = logit + B_ROWS;                       // B doubles
    unsigned short* Wp = (unsigned short*)(l1rows + B_ROWS);  // 4 MB packed W1 hi/lo

    hipMemsetAsync(d_ws, 0, (size_t)B_ROWS * sizeof(double), stream);

    pack_w1<<<512, 256, 0, stream>>>(W1, Wp);
    dim3 g1(B_ROWS / 64, 2);
    predictor_gemm<<<g1, 256, 0, stream>>>(x, Wp, b1, W2, logit);
    select_and_write<<<B_ROWS, 256, 0, stream>>>(x, W1, b1, W2, b2, logit,
                                                 out_sparse, out_mask,
                                                 out_sparsity, out_actual, l1rows);
    finalize_l1<<<1, 256, 0, stream>>>(l1rows, out_l1);
}

// Round 4
// 496.273 us; speedup vs baseline: 1.7755x; 1.7755x over previous
//
#include <hip/hip_runtime.h>
#include <math.h>

#define B_ROWS 16384
#define D_DIM  2048
#define H_DIM  512

typedef __attribute__((ext_vector_type(8))) short  s16x8;  // 8 bf16
typedef __attribute__((ext_vector_type(4))) float  f32x4;  // MFMA acc

union U8 { unsigned short us[8]; s16x8 v; };

static __device__ __forceinline__ unsigned short f2bf(float f) {
    unsigned u = __float_as_uint(f);
    u += 0x7FFFu + ((u >> 16) & 1u);   // RNE (no NaN inputs here)
    return (unsigned short)(u >> 16);
}

// ---------------- Kernel 0: pack W1 -> bf16 hi/lo in MFMA B-fragment order ----------------
// Fragment layout (16x16x32): lane l holds B[k=(l>>4)*8+j][n=l&15], j=0..7.
// Wp[type][s=k>>5][NtG=n>>4][lane][j], 2 types x 64 s x 32 Nt x 64 lanes x 8 bf16 = 4 MB.
__global__ __launch_bounds__(256) void pack_w1(
    const float* __restrict__ W1, unsigned short* __restrict__ Wp)
{
    const int gid = blockIdx.x * 256 + threadIdx.x;   // 131072 = 256 k-octets x 512 n
    const int ko = gid >> 9;          // k-octet 0..255
    const int n  = gid & 511;
    U8 h8, l8;
    #pragma unroll
    for (int j = 0; j < 8; ++j) {
        const float w = W1[(size_t)(ko * 8 + j) * H_DIM + n];
        const unsigned short h = f2bf(w);
        const float hf = __uint_as_float((unsigned)h << 16);
        h8.us[j] = h;
        l8.us[j] = f2bf(w - hf);
    }
    const int s    = ko >> 2;
    const int lane = (n & 15) | ((ko & 3) << 4);
    const int Nt   = n >> 4;
    const size_t baseH = ((((size_t)0 * 64 + s) * 32 + Nt) * 64 + lane) * 8;
    const size_t baseL = ((((size_t)1 * 64 + s) * 32 + Nt) * 64 + lane) * 8;
    *(s16x8*)(Wp + baseH) = h8.v;
    *(s16x8*)(Wp + baseL) = l8.v;
}

// ---------------- Kernel 1: predictor GEMM via bf16 MFMA, 4-product split ----------------
// Block: 64 rows x 256 cols, 256 threads (4 waves, one per 64-col slice).
// (xh+xl)(wh+wl): 64 MFMA/step -> fp32-GEMM-equivalent accuracy. A via LDS dbuf,
// B frags direct global->VGPR from packed Wp (L2-resident).
__global__ __launch_bounds__(256, 2) void predictor_gemm(
    const float* __restrict__ x, const unsigned short* __restrict__ Wp,
    const float* __restrict__ b1, const float* __restrict__ W2,
    double* __restrict__ logit)
{
    __shared__ __align__(16) unsigned short Abuf[2][2][4 * 64 * 8];

    const int tid = threadIdx.x;
    const int l   = tid & 63;
    const int Nw  = tid >> 6;
    const int bx  = blockIdx.x;
    const int by  = blockIdx.y;
    const int rowBase = bx * 64;

    const int sm = tid >> 2;
    const int sko = tid & 3;
    const float* xrow_p = x + (size_t)(rowBase + sm) * D_DIM + sko * 8;
    const int aMt   = sm >> 4;
    const int aLane = (sm & 15) | (sko << 4);
    unsigned short* aDstH[2] = {&Abuf[0][0][aMt * 512 + aLane * 8],
                                &Abuf[1][0][aMt * 512 + aLane * 8]};
    unsigned short* aDstL[2] = {&Abuf[0][1][aMt * 512 + aLane * 8],
                                &Abuf[1][1][aMt * 512 + aLane * 8]};

    const s16x8* WpV = (const s16x8*)Wp;
    const int NtBase = by * 16 + Nw * 4;

    f32x4 acc[4][4];
    #pragma unroll
    for (int mt = 0; mt < 4; ++mt)
        #pragma unroll
        for (int nt = 0; nt < 4; ++nt)
            acc[mt][nt] = {0.f, 0.f, 0.f, 0.f};

    float4 xa = *(const float4*)(xrow_p);
    float4 xb = *(const float4*)(xrow_p + 4);
    {
        U8 h8, l8;
        const float xv[8] = {xa.x, xa.y, xa.z, xa.w, xb.x, xb.y, xb.z, xb.w};
        #pragma unroll
        for (int i = 0; i < 8; ++i) {
            const unsigned short h = f2bf(xv[i]);
            h8.us[i] = h;
            l8.us[i] = f2bf(xv[i] - __uint_as_float((unsigned)h << 16));
        }
        *(s16x8*)aDstH[0] = h8.v;
        *(s16x8*)aDstL[0] = l8.v;
    }
    s16x8 Bh[4], Bl[4];
    #pragma unroll
    for (int nt = 0; nt < 4; ++nt) {
        Bh[nt] = WpV[((0 * 64 + 0) * 32 + NtBase + nt) * 64 + l];
        Bl[nt] = WpV[((1 * 64 + 0) * 32 + NtBase + nt) * 64 + l];
    }
    __syncthreads();

    for (int s = 0; s < 64; ++s) {
        const int cur = s & 1, nxt = cur ^ 1;
        s16x8 BhN[4], BlN[4];
        if (s < 63) {
            #pragma unroll
            for (int nt = 0; nt < 4; ++nt) {
                BhN[nt] = WpV[((0 * 64 + (s + 1)) * 32 + NtBase + nt) * 64 + l];
                BlN[nt] = WpV[((1 * 64 + (s + 1)) * 32 + NtBase + nt) * 64 + l];
            }
            xa = *(const float4*)(xrow_p + (s + 1) * 32);
            xb = *(const float4*)(xrow_p + (s + 1) * 32 + 4);
        }

        s16x8 Ah[4], Al[4];
        #pragma unroll
        for (int mt = 0; mt < 4; ++mt) {
            Ah[mt] = *(const s16x8*)&Abuf[cur][0][mt * 512 + l * 8];
            Al[mt] = *(const s16x8*)&Abuf[cur][1][mt * 512 + l * 8];
        }

        // 64 MFMAs: (hi+lo)x(hi+lo) full split
        #pragma unroll
        for (int mt = 0; mt < 4; ++mt)
            #pragma unroll
            for (int nt = 0; nt < 4; ++nt) {
                acc[mt][nt] = __builtin_amdgcn_mfma_f32_16x16x32_bf16(Ah[mt], Bh[nt], acc[mt][nt], 0, 0, 0);
                acc[mt][nt] = __builtin_amdgcn_mfma_f32_16x16x32_bf16(Al[mt], Bh[nt], acc[mt][nt], 0, 0, 0);
                acc[mt][nt] = __builtin_amdgcn_mfma_f32_16x16x32_bf16(Ah[mt], Bl[nt], acc[mt][nt], 0, 0, 0);
                acc[mt][nt] = __builtin_amdgcn_mfma_f32_16x16x32_bf16(Al[mt], Bl[nt], acc[mt][nt], 0, 0, 0);
            }

        if (s < 63) {
            U8 h8, l8;
            const float xv[8] = {xa.x, xa.y, xa.z, xa.w, xb.x, xb.y, xb.z, xb.w};
            #pragma unroll
            for (int i = 0; i < 8; ++i) {
                const unsigned short h = f2bf(xv[i]);
                h8.us[i] = h;
                l8.us[i] = f2bf(xv[i] - __uint_as_float((unsigned)h << 16));
            }
            *(s16x8*)aDstH[nxt] = h8.v;
            *(s16x8*)aDstL[nxt] = l8.v;
            #pragma unroll
            for (int nt = 0; nt < 4; ++nt) { Bh[nt] = BhN[nt]; Bl[nt] = BlN[nt]; }
        }
        __syncthreads();
    }

    // epilogue: +b1, relu, fp64 dot with W2, cross-lane reduce, atomic
    float  b1v[4];
    double w2v[4];
    #pragma unroll
    for (int nt = 0; nt < 4; ++nt) {
        const int j = by * 256 + (Nw * 4 + nt) * 16 + (l & 15);
        b1v[nt] = b1[j];
        w2v[nt] = (double)W2[j];
    }
    #pragma unroll
    for (int mt = 0; mt < 4; ++mt)
        #pragma unroll
        for (int reg = 0; reg < 4; ++reg) {
            double p = 0.0;
            #pragma unroll
            for (int nt = 0; nt < 4; ++nt) {
                const float h = acc[mt][nt][reg] + b1v[nt];
                if (h > 0.0f) p = fma((double)h, w2v[nt], p);
            }
            #pragma unroll
            for (int m2 = 1; m2 < 16; m2 <<= 1) p += __shfl_xor(p, m2, 64);
            if ((l & 15) == 0)
                atomicAdd(&logit[rowBase + mt * 16 + ((l >> 4) & 3) * 4 + reg], p);
        }
}

// ------------- Kernel 2: wave-per-row radix select + writeback (barrier-free) -------------
// One wave owns one row: 32 values/lane in VGPRs, per-wave 256-bin LDS histogram with
// 4-way sub-counter replication (lane&3) to cut hot-bin same-address serialization.
__global__ __launch_bounds__(256) void select_and_write(
    const float* __restrict__ x, const float* __restrict__ b2,
    const double* __restrict__ logit,
    float* __restrict__ out_sparse, float* __restrict__ out_mask,
    float* __restrict__ out_sparsity, float* __restrict__ out_actual,
    double* __restrict__ l1rows)
{
    __shared__ int hist[4][1024];    // per wave: 256 bins x 4 sub-counters

    const int tid = threadIdx.x;
    const int w = tid >> 6, l = tid & 63;
    const int row = blockIdx.x * 4 + w;
    int* hw = hist[w];

    const float4* x4 = (const float4*)(x + (size_t)row * D_DIM);
    float4 vv[8];
    #pragma unroll
    for (int i = 0; i < 8; ++i) vv[i] = x4[i * 64 + l];   // elems (i*64+l)*4..+3

    // k from logit (all lanes compute identically; wave-uniform)
    const double L = logit[row] + (double)b2[0];
    const double sig = 1.0 / (1.0 + exp(-L));
    const double s = 0.05 + 0.25 * sig;                 // MIN_S + (MAX_S-MIN_S)*sig
    int k = (int)rint(2048.0 * (1.0 - s));              // half-even == np.round
    if (k < 1) k = 1;
    if (k > 2048) k = 2048;
    if (l == 0) out_sparsity[row] = (float)s;

    int krem = k;                 // rank of k-th SMALLEST |x|
    unsigned prefix = 0;

    #pragma unroll
    for (int pass = 0; pass < 4; ++pass) {
        const int shift = 24 - pass * 8;
        const unsigned pmask = (pass == 0) ? 0u : (0xFFFFFFFFu << (shift + 8));

        #pragma unroll
        for (int j = 0; j < 4; ++j)
            ((int4*)hw)[l + 64 * j] = int4{0, 0, 0, 0};
        __builtin_amdgcn_wave_barrier();
        __threadfence_block();   // lgkmcnt drain; wave-synchronous, no s_barrier

        #pragma unroll
        for (int i = 0; i < 8; ++i) {
            const float qq[4] = {vv[i].x, vv[i].y, vv[i].z, vv[i].w};
            #pragma unroll
            for (int c = 0; c < 4; ++c) {
                const unsigned ub = __float_as_uint(qq[c]) & 0x7FFFFFFFu;
                if (pass == 0 || (ub & pmask) == prefix)
                    atomicAdd(&hw[((ub >> shift) & 255) * 4 + (l & 3)], 1);
            }
        }
        __builtin_amdgcn_wave_barrier();
        __threadfence_block();

        // scan: lane l owns bins 4l..4l+3 (each bin = one int4 of sub-counters)
        int b_[4], tot = 0;
        #pragma unroll
        for (int j = 0; j < 4; ++j) {
            const int4 c4 = ((const int4*)hw)[4 * l + j];
            b_[j] = c4.x + c4.y + c4.z + c4.w;
            tot += b_[j];
        }
        int sc = tot;
        #pragma unroll
        for (int off = 1; off < 64; off <<= 1) {
            const int n = __shfl_up(sc, off);
            if (l >= off) sc += n;
        }
        int cum = sc - tot;           // elems in bins < 4l
        int found = 0;
        #pragma unroll
        for (int j = 0; j < 4; ++j) {
            if (krem > cum && krem <= cum + b_[j])
                found = ((4 * l + j) << 12) | (krem - cum);   // one lane-j only
            cum += b_[j];
        }
        #pragma unroll
        for (int m2 = 1; m2 < 64; m2 <<= 1) found |= __shfl_xor(found, m2);
        prefix |= ((unsigned)(found >> 12)) << shift;
        krem = found & 0xFFF;
    }
    const unsigned thr = prefix;   // exact bit pattern of k-th smallest |x|

    // writeback: mask = (|x| > thr), bitwise-identical to reference compare
    float4* os4 = (float4*)(out_sparse + (size_t)row * D_DIM);
    float4* om4 = (float4*)(out_mask   + (size_t)row * D_DIM);
    int cnt = 0;
    double lp = 0.0;
    #pragma unroll
    for (int i = 0; i < 8; ++i) {
        const float qq[4] = {vv[i].x, vv[i].y, vv[i].z, vv[i].w};
        float sq[4], mq[4];
        #pragma unroll
        for (int c = 0; c < 4; ++c) {
            const unsigned ub = __float_as_uint(qq[c]) & 0x7FFFFFFFu;
            const bool keep = (ub > thr);
            mq[c] = keep ? 1.0f : 0.0f;
            sq[c] = keep ? qq[c] : 0.0f;
            cnt += keep ? 1 : 0;
            if (keep) lp += (double)fabsf(qq[c]);
        }
        os4[i * 64 + l] = float4{sq[0], sq[1], sq[2], sq[3]};
        om4[i * 64 + l] = float4{mq[0], mq[1], mq[2], mq[3]};
    }
    #pragma unroll
    for (int m2 = 1; m2 < 64; m2 <<= 1) {
        lp  += __shfl_xor(lp, m2);
        cnt += __shfl_xor(cnt, m2);
    }
    if (l == 0) {
        l1rows[row] = lp;
        out_actual[row] = (float)cnt * (1.0f / 2048.0f);
    }
}

// ---------------- Kernel 3: reduce row L1 sums -> l1_reg ----------------
__global__ __launch_bounds__(256) void finalize_l1(
    const double* __restrict__ l1rows, float* __restrict__ out_l1)
{
    __shared__ double sh[256];
    double s = 0.0;
    for (int i = threadIdx.x; i < B_ROWS; i += 256) s += l1rows[i];
    sh[threadIdx.x] = s;
    __syncthreads();
    for (int st = 128; st > 0; st >>= 1) {
        if (threadIdx.x < st) sh[threadIdx.x] += sh[threadIdx.x + st];
        __syncthreads();
    }
    if (threadIdx.x == 0) out_l1[0] = (float)(sh[0] / (double)B_ROWS);
}

extern "C" void kernel_launch(void* const* d_in, const int* in_sizes, int n_in,
                              void* d_out, int out_size, void* d_ws, size_t ws_size,
                              hipStream_t stream) {
    const float* x  = (const float*)d_in[0];
    const float* W1 = (const float*)d_in[1];
    const float* b1 = (const float*)d_in[2];
    const float* W2 = (const float*)d_in[3];
    const float* b2 = (const float*)d_in[4];

    float* out = (float*)d_out;
    float* out_sparse   = out;                                   // B*D
    float* out_mask     = out + (size_t)B_ROWS * D_DIM;          // B*D
    float* out_sparsity = out + 2ull * B_ROWS * D_DIM;           // B
    float* out_actual   = out_sparsity + B_ROWS;                 // B
    float* out_l1       = out_actual + B_ROWS;                   // 1

    double* logit  = (double*)d_ws;                        // B doubles (atomics)
    double* l1rows = logit + B_ROWS;                       // B doubles
    unsigned short* Wp = (unsigned short*)(l1rows + B_ROWS);  // 4 MB packed W1 hi/lo

    hipMemsetAsync(d_ws, 0, (size_t)B_ROWS * sizeof(double), stream);

    pack_w1<<<512, 256, 0, stream>>>(W1, Wp);
    dim3 g1(B_ROWS / 64, 2);
    predictor_gemm<<<g1, 256, 0, stream>>>(x, Wp, b1, W2, logit);
    select_and_write<<<B_ROWS / 4, 256, 0, stream>>>(x, b2, logit, out_sparse, out_mask,
                                                     out_sparsity, out_actual, l1rows);
    finalize_l1<<<1, 256, 0, stream>>>(l1rows, out_l1);
}